// Round 3
// baseline (241.770 us; speedup 1.0000x reference)
//
#include <hip/hip_runtime.h>

typedef __attribute__((ext_vector_type(8))) short short8;
typedef __attribute__((ext_vector_type(4))) float f32x4;

#define BATCH 32
#define LSEQ  512
#define DIN   256
#define FDIM  256
#define KTOT  768            // 3 taps * 256 channels
#define MT    32             // conv rows per block
#define BK    32             // K-chunk
#define PADA  264            // 256 + 8 shorts row stride for A tile

__device__ __forceinline__ short f2bf(float f) {
    union { float f; unsigned u; } v; v.f = f;
    unsigned r = v.u + 0x7FFFu + ((v.u >> 16) & 1u);   // RNE
    return (short)(r >> 16);
}

// ---------------- prep: per-batch scan -> frame index table (blocks 0..31) + weight repack ----------------
// fidx[b*M + f] = source row (b*512 + phoneme) for frame f, or -1 past the end.
// Weight repack: [768][256] f32 -> bf16 chunks wt[(k>>5)*256 + n][k&31]
__global__ __launch_bounds__(512)
void prep_kernel(const int* __restrict__ dur, int* __restrict__ fidx, int M,
                 const float* __restrict__ w1, const float* __restrict__ w2,
                 short* __restrict__ wt1, short* __restrict__ wt2) {
    __shared__ int s[LSEQ];
    const int t = threadIdx.x, b = blockIdx.x;
    if (b < BATCH) {
        s[t] = dur[b * LSEQ + t];
        __syncthreads();
        for (int off = 1; off < LSEQ; off <<= 1) {
            int v = (t >= off) ? s[t - off] : 0;
            __syncthreads();
            s[t] += v;
            __syncthreads();
        }
        // sentinel fill, then scatter the inverse map
        for (int f = t; f < M; f += 512) fidx[b * M + f] = -1;
        __syncthreads();
        int lo = (t == 0) ? 0 : s[t - 1];
        int hi = s[t];
        if (hi > M) hi = M;
        for (int j = lo; j < hi; j++) fidx[b * M + j] = b * LSEQ + t;
    } else {
        const int id = (b - BATCH) * 512 + t;          // 0..196607, coalesced read
        const int n = id & 255, k = id >> 8;
        const int dst = (((k >> 5) * FDIM) + n) * BK + (k & 31);
        wt1[dst] = f2bf(w1[id]);
        wt2[dst] = f2bf(w2[id]);
    }
}

// ------------- heterogeneous kernel: expand blocks (0..nexp-1) + conv blocks -------------
// Expand: one wave per output frame, pure gather/copy via precomputed fidx.
// Conv(K=3) as implicit-im2col GEMM + bias + LN + ReLU; A staged to LDS once,
// barrier-free K loop, B fragments straight from L2-resident prepped weights.
template<bool AF32, bool FUSE>
__global__ __launch_bounds__(256)
void conv_ln_expand(const void* __restrict__ Asrc, const short* __restrict__ Bt,
                    const float* __restrict__ cb, const float* __restrict__ g,
                    const float* __restrict__ bta, const float* __restrict__ lw,
                    const float* __restrict__ lb, short* __restrict__ Hout,
                    float* __restrict__ Dout,
                    const float4* __restrict__ x4, const int* __restrict__ fidx,
                    float4* __restrict__ out4, int M, int nexp, int ebase)
{
    __shared__ short As[34][PADA];      // ~17.6 KB
    __shared__ float redS[MT][4];
    __shared__ float redQ[MT][4];
    __shared__ float redD[MT][4];
    __shared__ float muS[MT];
    __shared__ float rsS[MT];

    const int tid  = threadIdx.x;
    const int lane = tid & 63;

    if (blockIdx.x < (unsigned)nexp) {
        // ---------------- expand part ----------------
        const int fr = (ebase + blockIdx.x) * 4 + (tid >> 6);
        const int idx = fidx[fr];                      // broadcast load
        const size_t obase = (size_t)fr * 64 + lane;
        if (idx >= 0) out4[obase] = x4[(size_t)idx * 64 + lane];
        else          out4[obase] = make_float4(0.f, 0.f, 0.f, 0.f);
        return;
    }

    // ---------------- conv part ----------------
    const int cblk = blockIdx.x - nexp;
    const int wave = tid >> 6;
    const int ml   = lane & 15;
    const int q    = lane >> 4;
    const int row0 = cblk * MT;
    const int bb   = row0 >> 9;          // batch (MT divides 512)
    const int r0   = row0 & (LSEQ - 1);  // row within batch

    // ---- stage A rows [r0-1 .. r0+32] into LDS (zeros outside batch) ----
    for (int idx = tid; idx < 34 * 32; idx += 256) {
        const int r = idx >> 5, part = idx & 31;
        const int l2 = r0 + r - 1;
        short8 v = {0, 0, 0, 0, 0, 0, 0, 0};
        if (l2 >= 0 && l2 < LSEQ) {
            const size_t off = ((size_t)(bb * LSEQ + l2)) * DIN + part * 8;
            if (AF32) {
                const float4* s4 = (const float4*)((const float*)Asrc + off);
                float4 u0 = s4[0], u1 = s4[1];
                v[0] = f2bf(u0.x); v[1] = f2bf(u0.y); v[2] = f2bf(u0.z); v[3] = f2bf(u0.w);
                v[4] = f2bf(u1.x); v[5] = f2bf(u1.y); v[6] = f2bf(u1.z); v[7] = f2bf(u1.w);
            } else {
                v = *(const short8*)((const short*)Asrc + off);
            }
        }
        *(short8*)&As[r][part * 8] = v;
    }
    __syncthreads();

    f32x4 acc[2][4];
    #pragma unroll
    for (int mt = 0; mt < 2; mt++)
        #pragma unroll
        for (int nt = 0; nt < 4; nt++)
            #pragma unroll
            for (int r = 0; r < 4; r++)
                acc[mt][nt][r] = 0.f;

    // ---- barrier-free K loop: 3 taps x 8 chunks of 32 ----
    const short* bptr = Bt + (size_t)(wave * 64 + ml) * BK + q * 8;
    #pragma unroll 1
    for (int tap = 0; tap < 3; tap++) {
        #pragma unroll
        for (int cc = 0; cc < 8; cc++) {
            short8 af0 = *(const short8*)&As[ml + tap][cc * 32 + q * 8];
            short8 af1 = *(const short8*)&As[16 + ml + tap][cc * 32 + q * 8];
            short8 b0 = *(const short8*)(bptr + 0 * 16 * BK);
            short8 b1 = *(const short8*)(bptr + 1 * 16 * BK);
            short8 b2 = *(const short8*)(bptr + 2 * 16 * BK);
            short8 b3 = *(const short8*)(bptr + 3 * 16 * BK);
            bptr += FDIM * BK;
            acc[0][0] = __builtin_amdgcn_mfma_f32_16x16x32_bf16(af0, b0, acc[0][0], 0, 0, 0);
            acc[0][1] = __builtin_amdgcn_mfma_f32_16x16x32_bf16(af0, b1, acc[0][1], 0, 0, 0);
            acc[0][2] = __builtin_amdgcn_mfma_f32_16x16x32_bf16(af0, b2, acc[0][2], 0, 0, 0);
            acc[0][3] = __builtin_amdgcn_mfma_f32_16x16x32_bf16(af0, b3, acc[0][3], 0, 0, 0);
            acc[1][0] = __builtin_amdgcn_mfma_f32_16x16x32_bf16(af1, b0, acc[1][0], 0, 0, 0);
            acc[1][1] = __builtin_amdgcn_mfma_f32_16x16x32_bf16(af1, b1, acc[1][1], 0, 0, 0);
            acc[1][2] = __builtin_amdgcn_mfma_f32_16x16x32_bf16(af1, b2, acc[1][2], 0, 0, 0);
            acc[1][3] = __builtin_amdgcn_mfma_f32_16x16x32_bf16(af1, b3, acc[1][3], 0, 0, 0);
        }
    }

    // ---------------- epilogue: bias + LayerNorm + ReLU (+ fused linear) ----------------
    float cbv[4], gv[4], bv[4], lwv[4];
    #pragma unroll
    for (int nt = 0; nt < 4; nt++) {
        const int col = wave * 64 + nt * 16 + ml;
        cbv[nt] = cb[col]; gv[nt] = g[col]; bv[nt] = bta[col];
        lwv[nt] = FUSE ? lw[col] : 0.f;
    }
    #pragma unroll
    for (int mt = 0; mt < 2; mt++)
        #pragma unroll
        for (int nt = 0; nt < 4; nt++)
            #pragma unroll
            for (int r = 0; r < 4; r++)
                acc[mt][nt][r] += cbv[nt];

    #pragma unroll
    for (int mt = 0; mt < 2; mt++)
        #pragma unroll
        for (int r = 0; r < 4; r++) {
            float ps = 0.f, pq = 0.f;
            #pragma unroll
            for (int nt = 0; nt < 4; nt++) { float v = acc[mt][nt][r]; ps += v; pq += v * v; }
            #pragma unroll
            for (int d = 1; d < 16; d <<= 1) { ps += __shfl_xor(ps, d); pq += __shfl_xor(pq, d); }
            if (ml == 0) { const int row = mt * 16 + q * 4 + r; redS[row][wave] = ps; redQ[row][wave] = pq; }
        }
    __syncthreads();
    if (tid < MT) {
        float S = 0.f, Q = 0.f;
        #pragma unroll
        for (int w = 0; w < 4; w++) { S += redS[tid][w]; Q += redQ[tid][w]; }
        const float mu  = S * (1.f / 256.f);
        const float var = Q * (1.f / 256.f) - mu * mu;
        muS[tid] = mu; rsS[tid] = rsqrtf(var + 1e-5f);
    }
    __syncthreads();

    if (!FUSE) {
        #pragma unroll
        for (int mt = 0; mt < 2; mt++)
            #pragma unroll
            for (int r = 0; r < 4; r++) {
                const int row = mt * 16 + q * 4 + r;
                const float mu = muS[row], rs = rsS[row];
                #pragma unroll
                for (int nt = 0; nt < 4; nt++) {
                    const int col = wave * 64 + nt * 16 + ml;
                    float v = (acc[mt][nt][r] - mu) * rs * gv[nt] + bv[nt];
                    v = fmaxf(v, 0.f);
                    Hout[(size_t)(row0 + row) * FDIM + col] = f2bf(v);
                }
            }
    } else {
        #pragma unroll
        for (int mt = 0; mt < 2; mt++)
            #pragma unroll
            for (int r = 0; r < 4; r++) {
                const int row = mt * 16 + q * 4 + r;
                const float mu = muS[row], rs = rsS[row];
                float pd = 0.f;
                #pragma unroll
                for (int nt = 0; nt < 4; nt++) {
                    float v = (acc[mt][nt][r] - mu) * rs * gv[nt] + bv[nt];
                    v = fmaxf(v, 0.f);
                    pd += v * lwv[nt];
                }
                #pragma unroll
                for (int d = 1; d < 16; d <<= 1) pd += __shfl_xor(pd, d);
                if (ml == 0) redD[row][wave] = pd;
            }
        __syncthreads();
        if (tid < MT) {
            float Dv = 0.f;
            #pragma unroll
            for (int w = 0; w < 4; w++) Dv += redD[tid][w];
            Dout[row0 + tid] = fmaxf(Dv + lb[0], 0.f);
        }
    }
}

extern "C" void kernel_launch(void* const* d_in, const int* in_sizes, int n_in,
                              void* d_out, int out_size, void* d_ws, size_t ws_size,
                              hipStream_t stream)
{
    const float* x   = (const float*)d_in[0];
    const int*   dur = (const int*)d_in[1];
    const float* c1w = (const float*)d_in[3];
    const float* c1b = (const float*)d_in[4];
    const float* g1  = (const float*)d_in[5];
    const float* b1  = (const float*)d_in[6];
    const float* c2w = (const float*)d_in[7];
    const float* c2b = (const float*)d_in[8];
    const float* g2  = (const float*)d_in[9];
    const float* b2  = (const float*)d_in[10];
    const float* lw  = (const float*)d_in[11];
    const float* lb  = (const float*)d_in[12];

    const int M = (out_size - BATCH * LSEQ) / (BATCH * DIN);   // 4096
    float* out     = (float*)d_out;
    float* dur_out = out + (size_t)BATCH * M * DIN;

    char* ws   = (char*)d_ws;
    int*  fidx = (int*)ws;                                      // 512 KB
    short* wt1 = (short*)(ws + (512 << 10));                    // 384 KB
    short* wt2 = (short*)(ws + (512 << 10) + (384 << 10));      // 384 KB
    short* h1  = (short*)(ws + (512 << 10) + 2 * (384 << 10));  // 8 MB

    const int NCONV = (BATCH * LSEQ) / MT;    // 512
    const int NEXP  = (BATCH * M) / 4;        // 32768 expand blocks total
    const int E1    = NEXP / 2;               // half with conv1, half with conv2
    const int E2    = NEXP - E1;

    hipLaunchKernelGGL(prep_kernel, dim3(BATCH + (KTOT * FDIM) / 512), dim3(512), 0, stream,
                       dur, fidx, M, c1w, c2w, wt1, wt2);
    hipLaunchKernelGGL((conv_ln_expand<true, false>), dim3(E1 + NCONV), dim3(256), 0, stream,
                       (const void*)x, wt1, c1b, g1, b1, (const float*)nullptr, (const float*)nullptr,
                       h1, (float*)nullptr,
                       (const float4*)x, fidx, (float4*)d_out, M, E1, 0);
    hipLaunchKernelGGL((conv_ln_expand<false, true>), dim3(E2 + NCONV), dim3(256), 0, stream,
                       (const void*)h1, wt2, c2b, g2, b2, lw, lb,
                       (short*)nullptr, dur_out,
                       (const float4*)x, fidx, (float4*)d_out, M, E2, E1);
}

// Round 4
// 205.541 us; speedup vs baseline: 1.1763x; 1.1763x over previous
//
#include <hip/hip_runtime.h>

typedef __attribute__((ext_vector_type(8))) short short8;
typedef __attribute__((ext_vector_type(4))) float f32x4;

#define BATCH 32
#define LSEQ  512
#define DIN   256
#define FDIM  256
#define KTOT  768            // 3 taps * 256 channels
#define MT    32             // conv rows per block
#define BK    32             // K-chunk
#define PADA  264            // 256 + 8 shorts row stride for A tile

__device__ __forceinline__ short f2bf(float f) {
    union { float f; unsigned u; } v; v.f = f;
    unsigned r = v.u + 0x7FFFu + ((v.u >> 16) & 1u);   // RNE
    return (short)(r >> 16);
}

// ---------------- prep: per-batch scan -> frame index table (blocks 0..31) + weight repack ----------------
// fidx[b*M + f] = source row (b*512 + phoneme) for frame f, or -1 past the end.
// Weight repack: [768][256] f32 -> bf16 chunks wt[(k>>5)*256 + n][k&31]
__global__ __launch_bounds__(512)
void prep_kernel(const int* __restrict__ dur, int* __restrict__ fidx, int M,
                 const float* __restrict__ w1, const float* __restrict__ w2,
                 short* __restrict__ wt1, short* __restrict__ wt2) {
    __shared__ int s[LSEQ];
    const int t = threadIdx.x, b = blockIdx.x;
    if (b < BATCH) {
        s[t] = dur[b * LSEQ + t];
        __syncthreads();
        for (int off = 1; off < LSEQ; off <<= 1) {
            int v = (t >= off) ? s[t - off] : 0;
            __syncthreads();
            s[t] += v;
            __syncthreads();
        }
        // sentinel fill, then scatter the inverse map
        for (int f = t; f < M; f += 512) fidx[b * M + f] = -1;
        __syncthreads();
        int lo = (t == 0) ? 0 : s[t - 1];
        int hi = s[t];
        if (hi > M) hi = M;
        for (int j = lo; j < hi; j++) fidx[b * M + j] = b * LSEQ + t;
    } else {
        const int id = (b - BATCH) * 512 + t;          // 0..196607, coalesced read
        const int n = id & 255, k = id >> 8;
        const int dst = (((k >> 5) * FDIM) + n) * BK + (k & 31);
        wt1[dst] = f2bf(w1[id]);
        wt2[dst] = f2bf(w2[id]);
    }
}

// ------------- conv(K=3) as implicit-im2col GEMM + bias + LN + ReLU -------------
// Block: 256 thr = 4 waves, MT=32 rows x full 256 cols (64 cols/wave).
// A (34 rows x 256 ch) staged to LDS ONCE; K-loop is barrier-free.
// B fragments loaded straight from L2-resident prepped weights (contiguous 1KB/wave/load).
template<bool AF32, bool FUSE>
__global__ __launch_bounds__(256)
void conv_ln(const void* __restrict__ Asrc, const short* __restrict__ Bt,
             const float* __restrict__ cb, const float* __restrict__ g,
             const float* __restrict__ bta, const float* __restrict__ lw,
             const float* __restrict__ lb, short* __restrict__ Hout,
             float* __restrict__ Dout)
{
    __shared__ short As[34][PADA];      // ~17.6 KB
    __shared__ float redS[MT][4];
    __shared__ float redQ[MT][4];
    __shared__ float redD[MT][4];
    __shared__ float muS[MT];
    __shared__ float rsS[MT];

    const int tid  = threadIdx.x;
    const int wave = tid >> 6;
    const int lane = tid & 63;
    const int ml   = lane & 15;
    const int q    = lane >> 4;
    const int row0 = blockIdx.x * MT;
    const int bb   = row0 >> 9;          // batch (MT divides 512)
    const int r0   = row0 & (LSEQ - 1);  // row within batch

    // ---- stage A rows [r0-1 .. r0+32] into LDS (zeros outside batch) ----
    for (int idx = tid; idx < 34 * 32; idx += 256) {
        const int r = idx >> 5, part = idx & 31;
        const int l2 = r0 + r - 1;
        short8 v = {0, 0, 0, 0, 0, 0, 0, 0};
        if (l2 >= 0 && l2 < LSEQ) {
            const size_t off = ((size_t)(bb * LSEQ + l2)) * DIN + part * 8;
            if (AF32) {
                const float4* s4 = (const float4*)((const float*)Asrc + off);
                float4 u0 = s4[0], u1 = s4[1];
                v[0] = f2bf(u0.x); v[1] = f2bf(u0.y); v[2] = f2bf(u0.z); v[3] = f2bf(u0.w);
                v[4] = f2bf(u1.x); v[5] = f2bf(u1.y); v[6] = f2bf(u1.z); v[7] = f2bf(u1.w);
            } else {
                v = *(const short8*)((const short*)Asrc + off);
            }
        }
        *(short8*)&As[r][part * 8] = v;
    }
    __syncthreads();

    f32x4 acc[2][4];
    #pragma unroll
    for (int mt = 0; mt < 2; mt++)
        #pragma unroll
        for (int nt = 0; nt < 4; nt++)
            #pragma unroll
            for (int r = 0; r < 4; r++)
                acc[mt][nt][r] = 0.f;

    // ---- barrier-free K loop: 3 taps x 8 chunks of 32 ----
    const short* bptr = Bt + (size_t)(wave * 64 + ml) * BK + q * 8;
    #pragma unroll 1
    for (int tap = 0; tap < 3; tap++) {
        #pragma unroll
        for (int cc = 0; cc < 8; cc++) {
            short8 af0 = *(const short8*)&As[ml + tap][cc * 32 + q * 8];
            short8 af1 = *(const short8*)&As[16 + ml + tap][cc * 32 + q * 8];
            short8 b0 = *(const short8*)(bptr + 0 * 16 * BK);
            short8 b1 = *(const short8*)(bptr + 1 * 16 * BK);
            short8 b2 = *(const short8*)(bptr + 2 * 16 * BK);
            short8 b3 = *(const short8*)(bptr + 3 * 16 * BK);
            bptr += FDIM * BK;
            acc[0][0] = __builtin_amdgcn_mfma_f32_16x16x32_bf16(af0, b0, acc[0][0], 0, 0, 0);
            acc[0][1] = __builtin_amdgcn_mfma_f32_16x16x32_bf16(af0, b1, acc[0][1], 0, 0, 0);
            acc[0][2] = __builtin_amdgcn_mfma_f32_16x16x32_bf16(af0, b2, acc[0][2], 0, 0, 0);
            acc[0][3] = __builtin_amdgcn_mfma_f32_16x16x32_bf16(af0, b3, acc[0][3], 0, 0, 0);
            acc[1][0] = __builtin_amdgcn_mfma_f32_16x16x32_bf16(af1, b0, acc[1][0], 0, 0, 0);
            acc[1][1] = __builtin_amdgcn_mfma_f32_16x16x32_bf16(af1, b1, acc[1][1], 0, 0, 0);
            acc[1][2] = __builtin_amdgcn_mfma_f32_16x16x32_bf16(af1, b2, acc[1][2], 0, 0, 0);
            acc[1][3] = __builtin_amdgcn_mfma_f32_16x16x32_bf16(af1, b3, acc[1][3], 0, 0, 0);
        }
    }

    // ---------------- epilogue: bias + LayerNorm + ReLU (+ fused linear) ----------------
    float cbv[4], gv[4], bv[4], lwv[4];
    #pragma unroll
    for (int nt = 0; nt < 4; nt++) {
        const int col = wave * 64 + nt * 16 + ml;
        cbv[nt] = cb[col]; gv[nt] = g[col]; bv[nt] = bta[col];
        lwv[nt] = FUSE ? lw[col] : 0.f;
    }
    #pragma unroll
    for (int mt = 0; mt < 2; mt++)
        #pragma unroll
        for (int nt = 0; nt < 4; nt++)
            #pragma unroll
            for (int r = 0; r < 4; r++)
                acc[mt][nt][r] += cbv[nt];

    #pragma unroll
    for (int mt = 0; mt < 2; mt++)
        #pragma unroll
        for (int r = 0; r < 4; r++) {
            float ps = 0.f, pq = 0.f;
            #pragma unroll
            for (int nt = 0; nt < 4; nt++) { float v = acc[mt][nt][r]; ps += v; pq += v * v; }
            #pragma unroll
            for (int d = 1; d < 16; d <<= 1) { ps += __shfl_xor(ps, d); pq += __shfl_xor(pq, d); }
            if (ml == 0) { const int row = mt * 16 + q * 4 + r; redS[row][wave] = ps; redQ[row][wave] = pq; }
        }
    __syncthreads();
    if (tid < MT) {
        float S = 0.f, Q = 0.f;
        #pragma unroll
        for (int w = 0; w < 4; w++) { S += redS[tid][w]; Q += redQ[tid][w]; }
        const float mu  = S * (1.f / 256.f);
        const float var = Q * (1.f / 256.f) - mu * mu;
        muS[tid] = mu; rsS[tid] = rsqrtf(var + 1e-5f);
    }
    __syncthreads();

    if (!FUSE) {
        #pragma unroll
        for (int mt = 0; mt < 2; mt++)
            #pragma unroll
            for (int r = 0; r < 4; r++) {
                const int row = mt * 16 + q * 4 + r;
                const float mu = muS[row], rs = rsS[row];
                #pragma unroll
                for (int nt = 0; nt < 4; nt++) {
                    const int col = wave * 64 + nt * 16 + ml;
                    float v = (acc[mt][nt][r] - mu) * rs * gv[nt] + bv[nt];
                    v = fmaxf(v, 0.f);
                    Hout[(size_t)(row0 + row) * FDIM + col] = f2bf(v);
                }
            }
    } else {
        #pragma unroll
        for (int mt = 0; mt < 2; mt++)
            #pragma unroll
            for (int r = 0; r < 4; r++) {
                const int row = mt * 16 + q * 4 + r;
                const float mu = muS[row], rs = rsS[row];
                float pd = 0.f;
                #pragma unroll
                for (int nt = 0; nt < 4; nt++) {
                    float v = (acc[mt][nt][r] - mu) * rs * gv[nt] + bv[nt];
                    v = fmaxf(v, 0.f);
                    pd += v * lwv[nt];
                }
                #pragma unroll
                for (int d = 1; d < 16; d <<= 1) pd += __shfl_xor(pd, d);
                if (ml == 0) redD[row][wave] = pd;
            }
        __syncthreads();
        if (tid < MT) {
            float Dv = 0.f;
            #pragma unroll
            for (int w = 0; w < 4; w++) Dv += redD[tid][w];
            Dout[row0 + tid] = fmaxf(Dv + lb[0], 0.f);
        }
    }
}

// ---------------- expand: 16 frames per block, 4 independent chains per wave ----------------
__global__ __launch_bounds__(256)
void expand_kernel(const float4* __restrict__ x4, const int* __restrict__ fidx,
                   float4* __restrict__ out4) {
    const int wave = threadIdx.x >> 6;
    const int lane = threadIdx.x & 63;
    const int fr0  = blockIdx.x * 16 + wave * 4;

    int idx[4];
    #pragma unroll
    for (int j = 0; j < 4; j++) idx[j] = fidx[fr0 + j];   // wave-broadcast loads

    float4 v[4];
    #pragma unroll
    for (int j = 0; j < 4; j++) {
        v[j] = make_float4(0.f, 0.f, 0.f, 0.f);
        if (idx[j] >= 0) v[j] = x4[(size_t)idx[j] * 64 + lane];   // 4 independent 1KB gathers
    }
    #pragma unroll
    for (int j = 0; j < 4; j++)
        out4[(size_t)(fr0 + j) * 64 + lane] = v[j];
}

extern "C" void kernel_launch(void* const* d_in, const int* in_sizes, int n_in,
                              void* d_out, int out_size, void* d_ws, size_t ws_size,
                              hipStream_t stream)
{
    const float* x   = (const float*)d_in[0];
    const int*   dur = (const int*)d_in[1];
    const float* c1w = (const float*)d_in[3];
    const float* c1b = (const float*)d_in[4];
    const float* g1  = (const float*)d_in[5];
    const float* b1  = (const float*)d_in[6];
    const float* c2w = (const float*)d_in[7];
    const float* c2b = (const float*)d_in[8];
    const float* g2  = (const float*)d_in[9];
    const float* b2  = (const float*)d_in[10];
    const float* lw  = (const float*)d_in[11];
    const float* lb  = (const float*)d_in[12];

    const int M = (out_size - BATCH * LSEQ) / (BATCH * DIN);   // 4096
    float* out     = (float*)d_out;
    float* dur_out = out + (size_t)BATCH * M * DIN;

    char* ws   = (char*)d_ws;
    int*  fidx = (int*)ws;                                      // 512 KB
    short* wt1 = (short*)(ws + (512 << 10));                    // 384 KB
    short* wt2 = (short*)(ws + (512 << 10) + (384 << 10));      // 384 KB
    short* h1  = (short*)(ws + (512 << 10) + 2 * (384 << 10));  // 8 MB

    hipLaunchKernelGGL(prep_kernel, dim3(BATCH + (KTOT * FDIM) / 512), dim3(512), 0, stream,
                       dur, fidx, M, c1w, c2w, wt1, wt2);
    hipLaunchKernelGGL((conv_ln<true, false>), dim3((BATCH * LSEQ) / MT), dim3(256), 0, stream,
                       (const void*)x, wt1, c1b, g1, b1, (const float*)nullptr, (const float*)nullptr,
                       h1, (float*)nullptr);
    hipLaunchKernelGGL((conv_ln<false, true>), dim3((BATCH * LSEQ) / MT), dim3(256), 0, stream,
                       (const void*)h1, wt2, c2b, g2, b2, lw, lb,
                       (short*)nullptr, dur_out);
    hipLaunchKernelGGL(expand_kernel, dim3((BATCH * M) / 16), dim3(256), 0, stream,
                       (const float4*)x, fidx, (float4*)d_out);
}